// Round 1
// baseline (1387.317 us; speedup 1.0000x reference)
//
#include <hip/hip_runtime.h>
#include <math.h>

#define N_NODES 100000
#define N_FEAT  512
#define HIDDEN  256
#define N_CLS   40
#define N_EDGES 1600000
#define K_HOPS  10
#define SCAN_BLOCKS 98   // 98*1024 = 100352 >= N_NODES+1

// class-chunked h layout: h[c][v][8] bf16, c = 0..4 (8 classes per chunk)
#define NCHUNK  5
#define CHSTRIDE (N_NODES * 8)      // shorts per chunk = 800000
#define NBLKN   391                 // ceil(N_NODES/256)
#define PUNITS  (NCHUNK * NBLKN)    // 1955 (chunk, node-block) units
#define PUPX    245                 // ceil(PUNITS/8) units per XCD
#define PGRID   (8 * PUPX)          // 1960 blocks, all co-resident at 8 blk/CU

typedef __attribute__((ext_vector_type(8))) short short8;   // 8 bf16
typedef __attribute__((ext_vector_type(4))) float f4_t;

__device__ __forceinline__ short f2bf(float f) {
    union { float f; unsigned u; } x; x.f = f;
    unsigned r = x.u + 0x7fffu + ((x.u >> 16) & 1u);  // RNE
    return (short)(r >> 16);
}

__device__ __forceinline__ float bf2f(short b) {
    union { unsigned u; float f; } x;
    x.u = ((unsigned)(unsigned short)b) << 16;
    return x.f;
}

// ---------------------------------------------------------------- prep kernels

__global__ __launch_bounds__(256) void init_deg_kernel(int* __restrict__ deg) {
    int v = blockIdx.x * 256 + threadIdx.x;
    if (v < N_NODES) deg[v] = 1;  // self-loop
}

__global__ __launch_bounds__(256) void count_dst_kernel(const int* __restrict__ dst,
                                                        int* __restrict__ deg) {
    int e = blockIdx.x * 256 + threadIdx.x;
    if (e < N_EDGES) atomicAdd(&deg[dst[e]], 1);
}

__global__ __launch_bounds__(256) void rsqrt_deg_kernel(const int* __restrict__ deg,
                                                        float* __restrict__ d) {
    int v = blockIdx.x * 256 + threadIdx.x;
    if (v < N_NODES) d[v] = rsqrtf((float)deg[v]);
}

// ---- 3-phase device-wide exclusive scan of deg -> rowptr/cursor (coalesced)

__global__ __launch_bounds__(1024) void scan_partial_kernel(const int* __restrict__ deg,
                                                            int* __restrict__ blocksum) {
    __shared__ int s[1024];
    int t = threadIdx.x;
    int idx = blockIdx.x * 1024 + t;
    s[t] = (idx < N_NODES) ? deg[idx] : 0;
    __syncthreads();
#pragma unroll
    for (int off = 512; off > 0; off >>= 1) {
        if (t < off) s[t] += s[t + off];
        __syncthreads();
    }
    if (t == 0) blocksum[blockIdx.x] = s[0];
}

__global__ __launch_bounds__(64) void scan_blocks_kernel(const int* __restrict__ blocksum,
                                                         int* __restrict__ blockoff) {
    if (threadIdx.x == 0) {
        int run = 0;
        for (int b = 0; b < SCAN_BLOCKS; ++b) { blockoff[b] = run; run += blocksum[b]; }
    }
}

__global__ __launch_bounds__(1024) void scan_write_kernel(const int* __restrict__ deg,
                                                          const int* __restrict__ blockoff,
                                                          int* __restrict__ rowptr,
                                                          int* __restrict__ cursor) {
    __shared__ int s[1024];
    int t = threadIdx.x;
    int idx = blockIdx.x * 1024 + t;
    int v = (idx < N_NODES) ? deg[idx] : 0;
    s[t] = v;
    __syncthreads();
#pragma unroll
    for (int off = 1; off < 1024; off <<= 1) {
        int add = (t >= off) ? s[t - off] : 0;
        __syncthreads();
        s[t] += add;
        __syncthreads();
    }
    int pre = s[t] - v + blockoff[blockIdx.x];  // exclusive prefix
    if (idx <= N_NODES) rowptr[idx] = pre;
    if (idx < N_NODES) cursor[idx] = pre;
}

__global__ __launch_bounds__(256) void scatter_edges_kernel(const int* __restrict__ src,
                                                            const int* __restrict__ dst,
                                                            const float* __restrict__ d,
                                                            int* __restrict__ cursor,
                                                            int2* __restrict__ epair) {
    int e = blockIdx.x * 256 + threadIdx.x;
    if (e >= N_EDGES) return;
    int u = src[e], v = dst[e];
    int pos = atomicAdd(&cursor[v], 1);
    int2 p;
    p.x = u;
    p.y = __float_as_int(d[u] * d[v]);
    epair[pos] = p;
}

__global__ __launch_bounds__(256) void scatter_self_kernel(const float* __restrict__ d,
                                                           int* __restrict__ cursor,
                                                           int2* __restrict__ epair) {
    int v = blockIdx.x * 256 + threadIdx.x;
    if (v >= N_NODES) return;
    int pos = atomicAdd(&cursor[v], 1);
    float dv = d[v];
    int2 p;
    p.x = v;
    p.y = __float_as_int(dv * dv);
    epair[pos] = p;
}

// W1 [512][256] f32 -> W1T [256][512] bf16 (col-major: per-col k contiguous)
__global__ __launch_bounds__(256) void cvt_w1_kernel(const float* __restrict__ W1,
                                                     short* __restrict__ W1T) {
    int lin = blockIdx.x * 256 + threadIdx.x;  // 131072
    int k = lin >> 8, n = lin & 255;
    W1T[n * 512 + k] = f2bf(W1[lin]);
}

// W2 [256][40] f32 -> W2T [64][256] bf16, rows >=40 zero
__global__ __launch_bounds__(256) void cvt_w2_kernel(const float* __restrict__ W2,
                                                     short* __restrict__ W2T) {
    int lin = blockIdx.x * 256 + threadIdx.x;  // 16384
    int n = lin >> 8, k = lin & 255;
    W2T[lin] = (n < N_CLS) ? f2bf(W2[k * N_CLS + n]) : (short)0;
}

// ---------------------------------------------------------------- fused MLP (MFMA)
// Block = 256 thr (4 waves), 64 rows.
// Pipelined: feat tile prefetched into regs during MFMA; A tile double-buffered
// in LDS; B (W1T) and W2 fragments loaded straight from L2 (no LDS staging).
// LDS = 18.4K (A dbuf) + 33.8K (sH) = 52.2 KB -> 3 blocks/CU (was 2 @ 79.9 KB).
__global__ __launch_bounds__(256, 3) void mlp_kernel(const float* __restrict__ feat,
                                                     const short* __restrict__ W1T,
                                                     const float* __restrict__ b1,
                                                     const short* __restrict__ W2T,
                                                     const float* __restrict__ b2,
                                                     const float* __restrict__ temp,
                                                     short* __restrict__ h,
                                                     float* __restrict__ TH) {
    __shared__ short A[2][64][72];    // 18432 B, double-buffered feat tile (bf16)
    __shared__ short sH[64][264];     // 33792 B, relu(h1) for phase B

    const int tid = threadIdx.x;
    const int rbase = blockIdx.x * 64;
    const int lane = tid & 63;
    const int wv = tid >> 6;       // wave 0..3
    const int quad = lane >> 4;    // 0..3
    const int l15 = lane & 15;

    f4_t acc[4][4];
#pragma unroll
    for (int m = 0; m < 4; ++m)
#pragma unroll
        for (int n = 0; n < 4; ++n) acc[m][n] = (f4_t)0.f;

    const int arow = tid >> 2;     // 0..63
    const int akq = tid & 3;       // 0..3
    const int grow = rbase + arow;
    const bool rv = (grow < N_NODES);
    const float* fp = feat + (size_t)(rv ? grow : 0) * N_FEAT + akq * 16;

    f4_t f0 = (f4_t)0.f, f1 = (f4_t)0.f, f2 = (f4_t)0.f, f3 = (f4_t)0.f;
    if (rv) {  // prefetch kt = 0
        const f4_t* p = (const f4_t*)fp;
        f0 = p[0]; f1 = p[1]; f2 = p[2]; f3 = p[3];
    }

    for (int kt = 0; kt < 8; ++kt) {
        {   // convert prefetched regs -> LDS A[kt&1]
            short8 lo, hi;
            lo[0]=f2bf(f0[0]); lo[1]=f2bf(f0[1]); lo[2]=f2bf(f0[2]); lo[3]=f2bf(f0[3]);
            lo[4]=f2bf(f1[0]); lo[5]=f2bf(f1[1]); lo[6]=f2bf(f1[2]); lo[7]=f2bf(f1[3]);
            hi[0]=f2bf(f2[0]); hi[1]=f2bf(f2[1]); hi[2]=f2bf(f2[2]); hi[3]=f2bf(f2[3]);
            hi[4]=f2bf(f3[0]); hi[5]=f2bf(f3[1]); hi[6]=f2bf(f3[2]); hi[7]=f2bf(f3[3]);
            short8* dstp = (short8*)&A[kt & 1][arow][akq * 16];
            dstp[0] = lo; dstp[1] = hi;
        }
        __syncthreads();
        if (kt < 7 && rv) {  // issue next tile's global loads; land under the MFMAs
            const f4_t* p = (const f4_t*)(fp + (kt + 1) * 64);
            f0 = p[0]; f1 = p[1]; f2 = p[2]; f3 = p[3];
        }
        const short* wb = W1T + kt * 64;
#pragma unroll
        for (int kk = 0; kk < 64; kk += 32) {
            short8 af[4], bf[4];
#pragma unroll
            for (int m = 0; m < 4; ++m)
                af[m] = *(const short8*)&A[kt & 1][m * 16 + l15][kk + quad * 8];
#pragma unroll
            for (int n = 0; n < 4; ++n)
                bf[n] = *(const short8*)(wb + (wv * 64 + n * 16 + l15) * 512 +
                                         kk + quad * 8);
#pragma unroll
            for (int m = 0; m < 4; ++m)
#pragma unroll
                for (int n = 0; n < 4; ++n)
                    acc[m][n] = __builtin_amdgcn_mfma_f32_16x16x32_bf16(af[m], bf[n],
                                                                        acc[m][n], 0, 0, 0);
        }
        // single barrier per kt: next write targets the other A buffer
    }

    // bias + relu -> sH (each wave owns a disjoint 64-col slice; sync after)
#pragma unroll
    for (int n = 0; n < 4; ++n) {
        int col = wv * 64 + n * 16 + l15;
        float bb = b1[col];
#pragma unroll
        for (int m = 0; m < 4; ++m)
#pragma unroll
            for (int r = 0; r < 4; ++r) {
                float v = acc[m][n][r] + bb;
                sH[m * 16 + quad * 4 + r][col] = f2bf(v > 0.f ? v : 0.f);
            }
    }
    __syncthreads();

    // phase B: out = sH @ W2 + b2 ; W2 fragments straight from L2 (32 KB, hot)
    f4_t accB[3];
#pragma unroll
    for (int n = 0; n < 3; ++n) accB[n] = (f4_t)0.f;
#pragma unroll
    for (int kk = 0; kk < 256; kk += 32) {
        short8 a = *(const short8*)&sH[wv * 16 + l15][kk + quad * 8];
#pragma unroll
        for (int n = 0; n < 3; ++n) {
            short8 b = *(const short8*)(W2T + (n * 16 + l15) * 256 + kk + quad * 8);
            accB[n] = __builtin_amdgcn_mfma_f32_16x16x32_bf16(a, b, accB[n], 0, 0, 0);
        }
    }
    float t0 = temp[0];
#pragma unroll
    for (int n = 0; n < 3; ++n) {
        int col = n * 16 + l15;
        if (col < N_CLS) {
            float bb = b2[col];
            int c = col >> 3, jj = col & 7;
#pragma unroll
            for (int r = 0; r < 4; ++r) {
                int grow2 = rbase + wv * 16 + quad * 4 + r;
                if (grow2 < N_NODES) {
                    float v = accB[n][r] + bb;
                    h[((size_t)c * N_NODES + grow2) * 8 + jj] = f2bf(v);
                    TH[grow2 * N_CLS + col] = t0 * v;
                }
            }
        }
    }
}

// ---------------------------------------------------------------- propagation
// Pull-based CSR SpMM over class-chunked h: one thread per (node, chunk).
// Unit u = (chunk, node-block); u = (bid%8)*PUPX + bid/8 gives each XCD a
// contiguous unit range -> <=2 chunks (<=3.2 MB gather set) per XCD L2.
__global__ __launch_bounds__(256, 8) void prop_kernel(const short* __restrict__ h,
                                                      short* __restrict__ hn,
                                                      const int* __restrict__ rowptr,
                                                      const int2* __restrict__ epair,
                                                      float* __restrict__ TH,
                                                      const float* __restrict__ temp,
                                                      int kidx) {
    int bid = blockIdx.x;
    int u = (bid & 7) * PUPX + (bid >> 3);
    if (u >= PUNITS) return;
    int c = u / NBLKN;
    int nb = u - c * NBLKN;
    int v = nb * 256 + threadIdx.x;
    if (v >= N_NODES) return;

    int s = rowptr[v], e = rowptr[v + 1];
    const short* hb = h + (size_t)c * CHSTRIDE;
    f4_t a0 = (f4_t)0.f, a1 = (f4_t)0.f;
    int j = s;
    for (; j + 4 <= e; j += 4) {
        int2 e0 = epair[j], e1 = epair[j + 1], e2 = epair[j + 2], e3 = epair[j + 3];
        short8 h0 = *(const short8*)(hb + (size_t)e0.x * 8);
        short8 h1 = *(const short8*)(hb + (size_t)e1.x * 8);
        short8 h2 = *(const short8*)(hb + (size_t)e2.x * 8);
        short8 h3 = *(const short8*)(hb + (size_t)e3.x * 8);
        float w0 = __int_as_float(e0.y), w1 = __int_as_float(e1.y);
        float w2 = __int_as_float(e2.y), w3 = __int_as_float(e3.y);
#pragma unroll
        for (int i = 0; i < 4; ++i) {
            a0[i] += w0 * bf2f(h0[i]) + w1 * bf2f(h1[i]) + w2 * bf2f(h2[i]) +
                     w3 * bf2f(h3[i]);
            a1[i] += w0 * bf2f(h0[4 + i]) + w1 * bf2f(h1[4 + i]) + w2 * bf2f(h2[4 + i]) +
                     w3 * bf2f(h3[4 + i]);
        }
    }
    for (; j < e; ++j) {
        int2 ep = epair[j];
        short8 hb8 = *(const short8*)(hb + (size_t)ep.x * 8);
        float w = __int_as_float(ep.y);
#pragma unroll
        for (int i = 0; i < 4; ++i) {
            a0[i] += w * bf2f(hb8[i]);
            a1[i] += w * bf2f(hb8[4 + i]);
        }
    }
    float tk = temp[kidx];
    short8 ob;
#pragma unroll
    for (int i = 0; i < 4; ++i) { ob[i] = f2bf(a0[i]); ob[4 + i] = f2bf(a1[i]); }
    *(short8*)(hn + (size_t)c * CHSTRIDE + (size_t)v * 8) = ob;   // coalesced
    float* pt = TH + (size_t)v * N_CLS + c * 8;                   // nt: don't evict h
    f4_t t0 = __builtin_nontemporal_load((const f4_t*)pt);
    f4_t t1 = __builtin_nontemporal_load(((const f4_t*)pt) + 1);
    t0 += tk * a0;
    t1 += tk * a1;
    __builtin_nontemporal_store(t0, (f4_t*)pt);
    __builtin_nontemporal_store(t1, ((f4_t*)pt) + 1);
}

// ---------------------------------------------------------------- log_softmax
__global__ __launch_bounds__(256) void lsm_kernel(float* __restrict__ out) {
    int wid = (blockIdx.x * 256 + threadIdx.x) >> 6;
    int lane = threadIdx.x & 63;
    if (wid >= N_NODES) return;
    float x = (lane < N_CLS) ? out[wid * N_CLS + lane] : -INFINITY;
    float m = x;
#pragma unroll
    for (int o = 32; o > 0; o >>= 1) m = fmaxf(m, __shfl_xor(m, o, 64));
    float e = (lane < N_CLS) ? expf(x - m) : 0.f;
    float s = e;
#pragma unroll
    for (int o = 32; o > 0; o >>= 1) s += __shfl_xor(s, o, 64);
    float r = x - m - logf(s);
    if (lane < N_CLS) out[wid * N_CLS + lane] = r;
}

// ---------------------------------------------------------------- launch

extern "C" void kernel_launch(void* const* d_in, const int* in_sizes, int n_in,
                              void* d_out, int out_size, void* d_ws, size_t ws_size,
                              hipStream_t stream) {
    const float* feat = (const float*)d_in[0];
    const float* W1   = (const float*)d_in[1];
    const float* b1   = (const float*)d_in[2];
    const float* W2   = (const float*)d_in[3];
    const float* b2   = (const float*)d_in[4];
    const float* temp = (const float*)d_in[5];
    const int*   src  = (const int*)d_in[6];
    const int*   dst  = (const int*)d_in[7];
    float* out = (float*)d_out;

    // workspace layout (bytes). deg region reused for W1T/W2T after scan.
    char* ws = (char*)d_ws;
    int*   deg    = (int*)(ws + 0);          //  400000 B (dead after scan_write)
    short* W1T    = (short*)(ws + 0);        //  262144 B (overlaps deg)
    short* W2T    = (short*)(ws + 262144);   //   32768 B
    float* dnorm  = (float*)(ws + 400000);   //  400000 B
    int*   rowptr = (int*)(ws + 800000);     //  400004 B
    int*   cursor = (int*)(ws + 1200016);    //  400000 B
    int2*  epair  = (int2*)(ws + 1600032);   // 13600000 B
    short* h0     = (short*)(ws + 15200032); //  8000000 B (bf16, chunked [5][N][8])
    short* h1     = (short*)(ws + 23200032); //  8000000 B
    int*   blocksum = (int*)(ws + 31200032); //   392 B
    int*   blockoff = (int*)(ws + 31200432); //   392 B  -> end 31200824

    init_deg_kernel<<<(N_NODES + 255) / 256, 256, 0, stream>>>(deg);
    count_dst_kernel<<<(N_EDGES + 255) / 256, 256, 0, stream>>>(dst, deg);
    rsqrt_deg_kernel<<<(N_NODES + 255) / 256, 256, 0, stream>>>(deg, dnorm);
    scan_partial_kernel<<<SCAN_BLOCKS, 1024, 0, stream>>>(deg, blocksum);
    scan_blocks_kernel<<<1, 64, 0, stream>>>(blocksum, blockoff);
    scan_write_kernel<<<SCAN_BLOCKS, 1024, 0, stream>>>(deg, blockoff, rowptr, cursor);
    cvt_w1_kernel<<<512, 256, 0, stream>>>(W1, W1T);
    cvt_w2_kernel<<<64, 256, 0, stream>>>(W2, W2T);
    scatter_edges_kernel<<<(N_EDGES + 255) / 256, 256, 0, stream>>>(src, dst, dnorm, cursor,
                                                                    epair);
    scatter_self_kernel<<<(N_NODES + 255) / 256, 256, 0, stream>>>(dnorm, cursor, epair);

    mlp_kernel<<<(N_NODES + 63) / 64, 256, 0, stream>>>(feat, W1T, b1, W2T, b2, temp, h0, out);

    short* hc = h0;
    short* hn = h1;
    for (int k = 0; k < K_HOPS; ++k) {
        prop_kernel<<<PGRID, 256, 0, stream>>>(hc, hn, rowptr, epair, out, temp, k + 1);
        short* t = hc; hc = hn; hn = t;
    }

    lsm_kernel<<<(N_NODES / 4), 256, 0, stream>>>(out);
}

// Round 2
// 1009.986 us; speedup vs baseline: 1.3736x; 1.3736x over previous
//
#include <hip/hip_runtime.h>
#include <math.h>

#define N_NODES 100000
#define N_FEAT  512
#define HIDDEN  256
#define N_CLS   40
#define N_EDGES 1600000
#define K_HOPS  10

#define NPART   8                    // src partitions for L2-locality edge ordering
#define PSZ     12500                // nodes per src-part
#define NPN     (NPART * N_NODES)    // 800000 virtual CSR rows (dst, src_part)
#define SCANB   782                  // ceil((NPN+1)/1024)
#define HROW    40                   // unpadded h row: 40 bf16 = 80 B

typedef __attribute__((ext_vector_type(8))) short short8;   // 8 bf16
typedef __attribute__((ext_vector_type(4))) float f4_t;

__device__ __forceinline__ short f2bf(float f) {
    union { float f; unsigned u; } x; x.f = f;
    unsigned r = x.u + 0x7fffu + ((x.u >> 16) & 1u);  // RNE
    return (short)(r >> 16);
}

__device__ __forceinline__ float bf2f(short b) {
    union { unsigned u; float f; } x;
    x.u = ((unsigned)(unsigned short)b) << 16;
    return x.f;
}

// ---------------------------------------------------------------- prep kernels

// degp[v*8+p] = 1 if p == part(v) (self-loop), else 0
__global__ __launch_bounds__(256) void init_degp_kernel(int* __restrict__ degp) {
    int idx = blockIdx.x * 256 + threadIdx.x;
    if (idx < NPN) {
        int v = idx >> 3, p = idx & 7;
        degp[idx] = (p == v / PSZ) ? 1 : 0;
    }
}

__global__ __launch_bounds__(256) void count_dst_kernel(const int* __restrict__ src,
                                                        const int* __restrict__ dst,
                                                        int* __restrict__ degp) {
    int e = blockIdx.x * 256 + threadIdx.x;
    if (e < N_EDGES) atomicAdd(&degp[dst[e] * NPART + src[e] / PSZ], 1);
}

// d[v] = rsqrt(sum_p degp[v*8+p])  (includes self-loop)
__global__ __launch_bounds__(256) void rsqrt_deg_kernel(const int* __restrict__ degp,
                                                        float* __restrict__ d) {
    int v = blockIdx.x * 256 + threadIdx.x;
    if (v < N_NODES) {
        int s = 0;
#pragma unroll
        for (int p = 0; p < NPART; ++p) s += degp[v * NPART + p];
        d[v] = rsqrtf((float)s);
    }
}

// ---- 3-phase device-wide exclusive scan of degp -> rowptrp/cursor (coalesced)

__global__ __launch_bounds__(1024) void scan_partial_kernel(const int* __restrict__ degp,
                                                            int* __restrict__ blocksum) {
    __shared__ int s[1024];
    int t = threadIdx.x;
    int idx = blockIdx.x * 1024 + t;
    s[t] = (idx < NPN) ? degp[idx] : 0;
    __syncthreads();
#pragma unroll
    for (int off = 512; off > 0; off >>= 1) {
        if (t < off) s[t] += s[t + off];
        __syncthreads();
    }
    if (t == 0) blocksum[blockIdx.x] = s[0];
}

// parallel single-block scan of SCANB block sums (serial loop would cost ~80us)
__global__ __launch_bounds__(1024) void scan_blocks_kernel(const int* __restrict__ blocksum,
                                                           int* __restrict__ blockoff) {
    __shared__ int s[1024];
    int t = threadIdx.x;
    int v = (t < SCANB) ? blocksum[t] : 0;
    s[t] = v;
    __syncthreads();
#pragma unroll
    for (int off = 1; off < 1024; off <<= 1) {
        int add = (t >= off) ? s[t - off] : 0;
        __syncthreads();
        s[t] += add;
        __syncthreads();
    }
    if (t < SCANB) blockoff[t] = s[t] - v;  // exclusive
}

__global__ __launch_bounds__(1024) void scan_write_kernel(const int* __restrict__ degp,
                                                          const int* __restrict__ blockoff,
                                                          int* __restrict__ rowptrp,
                                                          int* __restrict__ cursor) {
    __shared__ int s[1024];
    int t = threadIdx.x;
    int idx = blockIdx.x * 1024 + t;
    int v = (idx < NPN) ? degp[idx] : 0;
    s[t] = v;
    __syncthreads();
#pragma unroll
    for (int off = 1; off < 1024; off <<= 1) {
        int add = (t >= off) ? s[t - off] : 0;
        __syncthreads();
        s[t] += add;
        __syncthreads();
    }
    int pre = s[t] - v + blockoff[blockIdx.x];  // exclusive prefix
    if (idx <= NPN) rowptrp[idx] = pre;
    if (idx < NPN) cursor[idx] = pre;
}

__global__ __launch_bounds__(256) void scatter_edges_kernel(const int* __restrict__ src,
                                                            const int* __restrict__ dst,
                                                            const float* __restrict__ d,
                                                            int* __restrict__ cursor,
                                                            int2* __restrict__ epair) {
    int e = blockIdx.x * 256 + threadIdx.x;
    if (e >= N_EDGES) return;
    int u = src[e], v = dst[e];
    int pos = atomicAdd(&cursor[v * NPART + u / PSZ], 1);
    int2 p;
    p.x = u;
    p.y = __float_as_int(d[u] * d[v]);
    epair[pos] = p;
}

__global__ __launch_bounds__(256) void scatter_self_kernel(const float* __restrict__ d,
                                                           int* __restrict__ cursor,
                                                           int2* __restrict__ epair) {
    int v = blockIdx.x * 256 + threadIdx.x;
    if (v >= N_NODES) return;
    int pos = atomicAdd(&cursor[v * NPART + v / PSZ], 1);
    float dv = d[v];
    int2 p;
    p.x = v;
    p.y = __float_as_int(dv * dv);
    epair[pos] = p;
}

// W1 [512][256] f32 -> W1T [256][512] bf16 (col-major: per-col k contiguous)
__global__ __launch_bounds__(256) void cvt_w1_kernel(const float* __restrict__ W1,
                                                     short* __restrict__ W1T) {
    int lin = blockIdx.x * 256 + threadIdx.x;  // 131072
    int k = lin >> 8, n = lin & 255;
    W1T[n * 512 + k] = f2bf(W1[lin]);
}

// W2 [256][40] f32 -> W2T [64][256] bf16, rows >=40 zero
__global__ __launch_bounds__(256) void cvt_w2_kernel(const float* __restrict__ W2,
                                                     short* __restrict__ W2T) {
    int lin = blockIdx.x * 256 + threadIdx.x;  // 16384
    int n = lin >> 8, k = lin & 255;
    W2T[lin] = (n < N_CLS) ? f2bf(W2[k * N_CLS + n]) : (short)0;
}

// ---------------------------------------------------------------- fused MLP (MFMA)
// Block = 256 thr (4 waves), 64 rows. DEPTH-2 register prefetch of feat
// (~940cy window >= ~900cy HBM latency; depth-1's ~470cy window stalled).
// B (W1T) and W2 fragments straight from L1/L2 (256KB, fully cached).
__global__ __launch_bounds__(256, 3) void mlp_kernel(const float* __restrict__ feat,
                                                     const short* __restrict__ W1T,
                                                     const float* __restrict__ b1,
                                                     const short* __restrict__ W2T,
                                                     const float* __restrict__ b2,
                                                     const float* __restrict__ temp,
                                                     short* __restrict__ h,
                                                     float* __restrict__ TH) {
    __shared__ short A[2][64][72];    // 18432 B, double-buffered feat tile (bf16)
    __shared__ short sH[64][264];     // 33792 B, relu(h1) for phase B

    const int tid = threadIdx.x;
    const int rbase = blockIdx.x * 64;
    const int lane = tid & 63;
    const int wv = tid >> 6;       // wave 0..3
    const int quad = lane >> 4;    // 0..3
    const int l15 = lane & 15;

    f4_t acc[4][4];
#pragma unroll
    for (int m = 0; m < 4; ++m)
#pragma unroll
        for (int n = 0; n < 4; ++n) acc[m][n] = (f4_t)0.f;

    const int arow = tid >> 2;     // 0..63
    const int akq = tid & 3;       // 0..3
    const int grow = rbase + arow;
    const bool rv = (grow < N_NODES);
    const float* fp = feat + (size_t)(rv ? grow : 0) * N_FEAT + akq * 16;

    f4_t fA[2][4];                 // depth-2 prefetch: 2 k-tiles in flight
#pragma unroll
    for (int b = 0; b < 2; ++b)
#pragma unroll
        for (int q = 0; q < 4; ++q) fA[b][q] = (f4_t)0.f;
    if (rv) {
        const f4_t* p0 = (const f4_t*)fp;
        const f4_t* p1 = (const f4_t*)(fp + 64);
#pragma unroll
        for (int q = 0; q < 4; ++q) { fA[0][q] = p0[q]; fA[1][q] = p1[q]; }
    }

#pragma unroll
    for (int kt = 0; kt < 8; ++kt) {
        const int b = kt & 1;
        {   // convert prefetched regs -> LDS A[b]
            short8 lo, hi;
            lo[0]=f2bf(fA[b][0][0]); lo[1]=f2bf(fA[b][0][1]);
            lo[2]=f2bf(fA[b][0][2]); lo[3]=f2bf(fA[b][0][3]);
            lo[4]=f2bf(fA[b][1][0]); lo[5]=f2bf(fA[b][1][1]);
            lo[6]=f2bf(fA[b][1][2]); lo[7]=f2bf(fA[b][1][3]);
            hi[0]=f2bf(fA[b][2][0]); hi[1]=f2bf(fA[b][2][1]);
            hi[2]=f2bf(fA[b][2][2]); hi[3]=f2bf(fA[b][2][3]);
            hi[4]=f2bf(fA[b][3][0]); hi[5]=f2bf(fA[b][3][1]);
            hi[6]=f2bf(fA[b][3][2]); hi[7]=f2bf(fA[b][3][3]);
            short8* dstp = (short8*)&A[b][arow][akq * 16];
            dstp[0] = lo; dstp[1] = hi;
        }
        __syncthreads();
        if (kt < 6 && rv) {  // refill freed buffer for kt+2; lands under 2 kt of MFMA
            const f4_t* p = (const f4_t*)(fp + (kt + 2) * 64);
#pragma unroll
            for (int q = 0; q < 4; ++q) fA[b][q] = p[q];
        }
        const short* wb = W1T + kt * 64;
#pragma unroll
        for (int kk = 0; kk < 64; kk += 32) {
            short8 af[4], bf[4];
#pragma unroll
            for (int n = 0; n < 4; ++n)
                bf[n] = *(const short8*)(wb + (wv * 64 + n * 16 + l15) * 512 +
                                         kk + quad * 8);
#pragma unroll
            for (int m = 0; m < 4; ++m)
                af[m] = *(const short8*)&A[b][m * 16 + l15][kk + quad * 8];
#pragma unroll
            for (int m = 0; m < 4; ++m)
#pragma unroll
                for (int n = 0; n < 4; ++n)
                    acc[m][n] = __builtin_amdgcn_mfma_f32_16x16x32_bf16(af[m], bf[n],
                                                                        acc[m][n], 0, 0, 0);
        }
        // single barrier per kt: next write targets the other A buffer
    }

    // bias + relu -> sH (each wave owns a disjoint 64-col slice; sync after)
#pragma unroll
    for (int n = 0; n < 4; ++n) {
        int col = wv * 64 + n * 16 + l15;
        float bb = b1[col];
#pragma unroll
        for (int m = 0; m < 4; ++m)
#pragma unroll
            for (int r = 0; r < 4; ++r) {
                float v = acc[m][n][r] + bb;
                sH[m * 16 + quad * 4 + r][col] = f2bf(v > 0.f ? v : 0.f);
            }
    }
    __syncthreads();

    // phase B: out = sH @ W2 + b2 ; W2 fragments straight from L1/L2 (32 KB, hot)
    f4_t accB[3];
#pragma unroll
    for (int n = 0; n < 3; ++n) accB[n] = (f4_t)0.f;
#pragma unroll
    for (int kk = 0; kk < 256; kk += 32) {
        short8 a = *(const short8*)&sH[wv * 16 + l15][kk + quad * 8];
#pragma unroll
        for (int n = 0; n < 3; ++n) {
            short8 b = *(const short8*)(W2T + (n * 16 + l15) * 256 + kk + quad * 8);
            accB[n] = __builtin_amdgcn_mfma_f32_16x16x32_bf16(a, b, accB[n], 0, 0, 0);
        }
    }
    float t0 = temp[0];
#pragma unroll
    for (int n = 0; n < 3; ++n) {
        int col = n * 16 + l15;
        if (col < N_CLS) {
            float bb = b2[col];
#pragma unroll
            for (int r = 0; r < 4; ++r) {
                int grow2 = rbase + wv * 16 + quad * 4 + r;
                if (grow2 < N_NODES) {
                    float v = accB[n][r] + bb;
                    h[(size_t)grow2 * HROW + col] = f2bf(v);
                    TH[grow2 * N_CLS + col] = t0 * v;
                }
            }
        }
    }
}

// ---------------------------------------------------------------- propagation
// Pull-based CSR SpMM. 5 lanes/node (coalesced 80B row gathers). Edges within
// each node's list are ordered by src-part (8 x 1MB parts); all threads sweep
// lists front-to-back, so the hot gather region is ~2-3 parts == L2-resident.
// Streams (epair/rowptr/hn/TH) are NT so they don't evict the hot h parts.
__global__ __launch_bounds__(256) void prop_kernel(const short* __restrict__ h,
                                                   short* __restrict__ hn,
                                                   const int* __restrict__ rowptrp,
                                                   const int2* __restrict__ epair,
                                                   float* __restrict__ TH,
                                                   const float* __restrict__ temp,
                                                   int kidx) {
    int gid = blockIdx.x * 256 + threadIdx.x;
    int v = gid / 5;
    if (v >= N_NODES) return;
    int c = gid - v * 5;  // class chunk 0..4 (8 classes each)
    int s = __builtin_nontemporal_load(rowptrp + v * NPART);
    int e = __builtin_nontemporal_load(rowptrp + v * NPART + NPART);
    const short* hc = h + c * 8;
    f4_t a0 = (f4_t)0.f, a1 = (f4_t)0.f;
    int j = s;
    for (; j + 4 <= e; j += 4) {
        long long r0 = __builtin_nontemporal_load((const long long*)(epair + j));
        long long r1 = __builtin_nontemporal_load((const long long*)(epair + j + 1));
        long long r2 = __builtin_nontemporal_load((const long long*)(epair + j + 2));
        long long r3 = __builtin_nontemporal_load((const long long*)(epair + j + 3));
        short8 h0 = *(const short8*)(hc + (size_t)(int)r0 * HROW);
        short8 h1 = *(const short8*)(hc + (size_t)(int)r1 * HROW);
        short8 h2 = *(const short8*)(hc + (size_t)(int)r2 * HROW);
        short8 h3 = *(const short8*)(hc + (size_t)(int)r3 * HROW);
        float w0 = __int_as_float((int)(r0 >> 32)), w1 = __int_as_float((int)(r1 >> 32));
        float w2 = __int_as_float((int)(r2 >> 32)), w3 = __int_as_float((int)(r3 >> 32));
#pragma unroll
        for (int i = 0; i < 4; ++i) {
            a0[i] += w0 * bf2f(h0[i]) + w1 * bf2f(h1[i]) + w2 * bf2f(h2[i]) +
                     w3 * bf2f(h3[i]);
            a1[i] += w0 * bf2f(h0[4 + i]) + w1 * bf2f(h1[4 + i]) + w2 * bf2f(h2[4 + i]) +
                     w3 * bf2f(h3[4 + i]);
        }
    }
    for (; j < e; ++j) {
        long long r = __builtin_nontemporal_load((const long long*)(epair + j));
        short8 hb8 = *(const short8*)(hc + (size_t)(int)r * HROW);
        float w = __int_as_float((int)(r >> 32));
#pragma unroll
        for (int i = 0; i < 4; ++i) {
            a0[i] += w * bf2f(hb8[i]);
            a1[i] += w * bf2f(hb8[4 + i]);
        }
    }
    float tk = temp[kidx];
    short8 ob;
#pragma unroll
    for (int i = 0; i < 4; ++i) { ob[i] = f2bf(a0[i]); ob[4 + i] = f2bf(a1[i]); }
    __builtin_nontemporal_store(ob, (short8*)(hn + (size_t)v * HROW + c * 8));
    float* pt = TH + (size_t)v * N_CLS + c * 8;
    f4_t t0 = __builtin_nontemporal_load((const f4_t*)pt);
    f4_t t1 = __builtin_nontemporal_load(((const f4_t*)pt) + 1);
    t0 += tk * a0;
    t1 += tk * a1;
    __builtin_nontemporal_store(t0, (f4_t*)pt);
    __builtin_nontemporal_store(t1, ((f4_t*)pt) + 1);
}

// ---------------------------------------------------------------- log_softmax
__global__ __launch_bounds__(256) void lsm_kernel(float* __restrict__ out) {
    int wid = (blockIdx.x * 256 + threadIdx.x) >> 6;
    int lane = threadIdx.x & 63;
    if (wid >= N_NODES) return;
    float x = (lane < N_CLS) ? out[wid * N_CLS + lane] : -INFINITY;
    float m = x;
#pragma unroll
    for (int o = 32; o > 0; o >>= 1) m = fmaxf(m, __shfl_xor(m, o, 64));
    float e = (lane < N_CLS) ? expf(x - m) : 0.f;
    float s = e;
#pragma unroll
    for (int o = 32; o > 0; o >>= 1) s += __shfl_xor(s, o, 64);
    float r = x - m - logf(s);
    if (lane < N_CLS) out[wid * N_CLS + lane] = r;
}

// ---------------------------------------------------------------- launch

extern "C" void kernel_launch(void* const* d_in, const int* in_sizes, int n_in,
                              void* d_out, int out_size, void* d_ws, size_t ws_size,
                              hipStream_t stream) {
    const float* feat = (const float*)d_in[0];
    const float* W1   = (const float*)d_in[1];
    const float* b1   = (const float*)d_in[2];
    const float* W2   = (const float*)d_in[3];
    const float* b2   = (const float*)d_in[4];
    const float* temp = (const float*)d_in[5];
    const int*   src  = (const int*)d_in[6];
    const int*   dst  = (const int*)d_in[7];
    float* out = (float*)d_out;

    // workspace layout (bytes). degp region reused for W1T/W2T after scan_write.
    char* ws = (char*)d_ws;
    int*   degp    = (int*)(ws + 0);          // 3,200,000 B (dead after scan_write)
    short* W1T     = (short*)(ws + 0);        //   262,144 B (overlaps degp)
    short* W2T     = (short*)(ws + 262144);   //    32,768 B (overlaps degp)
    float* dnorm   = (float*)(ws + 3200000);  //   400,000 B
    int*   rowptrp = (int*)(ws + 3600000);    // 3,200,004 B
    int*   cursor  = (int*)(ws + 6800016);    // 3,200,000 B
    int2*  epair   = (int2*)(ws + 10000016);  // 13,600,000 B
    short* h0      = (short*)(ws + 23600016); //  8,000,000 B (bf16, [N][40])
    short* h1      = (short*)(ws + 31600016); //  8,000,000 B
    int*   blocksum = (int*)(ws + 39600016);  //     3,128 B
    int*   blockoff = (int*)(ws + 39603152);  //     3,128 B  -> end 39,606,280

    init_degp_kernel<<<(NPN + 255) / 256, 256, 0, stream>>>(degp);
    count_dst_kernel<<<(N_EDGES + 255) / 256, 256, 0, stream>>>(src, dst, degp);
    rsqrt_deg_kernel<<<(N_NODES + 255) / 256, 256, 0, stream>>>(degp, dnorm);
    scan_partial_kernel<<<SCANB, 1024, 0, stream>>>(degp, blocksum);
    scan_blocks_kernel<<<1, 1024, 0, stream>>>(blocksum, blockoff);
    scan_write_kernel<<<SCANB, 1024, 0, stream>>>(degp, blockoff, rowptrp, cursor);
    cvt_w1_kernel<<<512, 256, 0, stream>>>(W1, W1T);
    cvt_w2_kernel<<<64, 256, 0, stream>>>(W2, W2T);
    scatter_edges_kernel<<<(N_EDGES + 255) / 256, 256, 0, stream>>>(src, dst, dnorm, cursor,
                                                                    epair);
    scatter_self_kernel<<<(N_NODES + 255) / 256, 256, 0, stream>>>(dnorm, cursor, epair);

    mlp_kernel<<<(N_NODES + 63) / 64, 256, 0, stream>>>(feat, W1T, b1, W2T, b2, temp, h0, out);

    short* hc = h0;
    short* hn = h1;
    for (int k = 0; k < K_HOPS; ++k) {
        prop_kernel<<<(N_NODES * 5 + 255) / 256, 256, 0, stream>>>(hc, hn, rowptrp, epair,
                                                                   out, temp, k + 1);
        short* t = hc; hc = hn; hn = t;
    }

    lsm_kernel<<<(N_NODES / 4), 256, 0, stream>>>(out);
}

// Round 3
// 852.478 us; speedup vs baseline: 1.6274x; 1.1848x over previous
//
#include <hip/hip_runtime.h>
#include <math.h>
#include <stdint.h>

#define N_NODES 100000
#define N_FEAT  512
#define HIDDEN  256
#define N_CLS   40
#define N_EDGES 1600000
#define K_HOPS  10

#define NPART   8                    // src partitions for L2-locality edge ordering
#define PSZ     12500                // nodes per src-part
#define NPN     (NPART * N_NODES)    // 800000 virtual CSR rows (dst, src_part)
#define SCANB   782                  // ceil((NPN+1)/1024)
#define HROW    40                   // h row: 40 bf16 = 80 B (16B-aligned since 80=5*16)

#define PB      51                   // nodes per prop block (255 active threads * 5)
#define PGRID   ((N_NODES + PB - 1) / PB)   // 1961
#define ECAP    2048                 // LDS epair slots (block avg ~870, max ~1000)

typedef __attribute__((ext_vector_type(8))) short short8;   // 8 bf16
typedef __attribute__((ext_vector_type(4))) float f4_t;

__device__ __forceinline__ short f2bf(float f) {
    union { float f; unsigned u; } x; x.f = f;
    unsigned r = x.u + 0x7fffu + ((x.u >> 16) & 1u);  // RNE
    return (short)(r >> 16);
}

__device__ __forceinline__ float bf2f(short b) {
    union { unsigned u; float f; } x;
    x.u = ((unsigned)(unsigned short)b) << 16;
    return x.f;
}

// packed f32x2 -> bf16x2 (RNE), single HW instr; no builtin on gfx950
__device__ __forceinline__ unsigned cvtpk(float lo, float hi) {
    unsigned r;
    asm("v_cvt_pk_bf16_f32 %0, %1, %2" : "=v"(r) : "v"(lo), "v"(hi));
    return r;
}

__device__ __forceinline__ void gload_lds16(const float* g, void* l) {
    __builtin_amdgcn_global_load_lds(
        (const __attribute__((address_space(1))) void*)g,
        (__attribute__((address_space(3))) void*)l, 16, 0, 0);
}

// ---------------------------------------------------------------- prep kernels

// degp[v*8+p] = 1 if p == part(v) (self-loop), else 0
__global__ __launch_bounds__(256) void init_degp_kernel(int* __restrict__ degp) {
    int idx = blockIdx.x * 256 + threadIdx.x;
    if (idx < NPN) {
        int v = idx >> 3, p = idx & 7;
        degp[idx] = (p == v / PSZ) ? 1 : 0;
    }
}

__global__ __launch_bounds__(256) void count_dst_kernel(const int* __restrict__ src,
                                                        const int* __restrict__ dst,
                                                        int* __restrict__ degp) {
    int e = blockIdx.x * 256 + threadIdx.x;
    if (e < N_EDGES) atomicAdd(&degp[dst[e] * NPART + src[e] / PSZ], 1);
}

__global__ __launch_bounds__(256) void rsqrt_deg_kernel(const int* __restrict__ degp,
                                                        float* __restrict__ d) {
    int v = blockIdx.x * 256 + threadIdx.x;
    if (v < N_NODES) {
        int s = 0;
#pragma unroll
        for (int p = 0; p < NPART; ++p) s += degp[v * NPART + p];
        d[v] = rsqrtf((float)s);
    }
}

// ---- 3-phase device-wide exclusive scan of degp -> rowptrp/cursor

__global__ __launch_bounds__(1024) void scan_partial_kernel(const int* __restrict__ degp,
                                                            int* __restrict__ blocksum) {
    __shared__ int s[1024];
    int t = threadIdx.x;
    int idx = blockIdx.x * 1024 + t;
    s[t] = (idx < NPN) ? degp[idx] : 0;
    __syncthreads();
#pragma unroll
    for (int off = 512; off > 0; off >>= 1) {
        if (t < off) s[t] += s[t + off];
        __syncthreads();
    }
    if (t == 0) blocksum[blockIdx.x] = s[0];
}

__global__ __launch_bounds__(1024) void scan_blocks_kernel(const int* __restrict__ blocksum,
                                                           int* __restrict__ blockoff) {
    __shared__ int s[1024];
    int t = threadIdx.x;
    int v = (t < SCANB) ? blocksum[t] : 0;
    s[t] = v;
    __syncthreads();
#pragma unroll
    for (int off = 1; off < 1024; off <<= 1) {
        int add = (t >= off) ? s[t - off] : 0;
        __syncthreads();
        s[t] += add;
        __syncthreads();
    }
    if (t < SCANB) blockoff[t] = s[t] - v;  // exclusive
}

__global__ __launch_bounds__(1024) void scan_write_kernel(const int* __restrict__ degp,
                                                          const int* __restrict__ blockoff,
                                                          int* __restrict__ rowptrp,
                                                          int* __restrict__ cursor) {
    __shared__ int s[1024];
    int t = threadIdx.x;
    int idx = blockIdx.x * 1024 + t;
    int v = (idx < NPN) ? degp[idx] : 0;
    s[t] = v;
    __syncthreads();
#pragma unroll
    for (int off = 1; off < 1024; off <<= 1) {
        int add = (t >= off) ? s[t - off] : 0;
        __syncthreads();
        s[t] += add;
        __syncthreads();
    }
    int pre = s[t] - v + blockoff[blockIdx.x];  // exclusive prefix
    if (idx <= NPN) rowptrp[idx] = pre;
    if (idx < NPN) cursor[idx] = pre;
}

// epair.x holds PRE-SCALED byte offset (u*80) so prop needs no multiply
__global__ __launch_bounds__(256) void scatter_edges_kernel(const int* __restrict__ src,
                                                            const int* __restrict__ dst,
                                                            const float* __restrict__ d,
                                                            int* __restrict__ cursor,
                                                            int2* __restrict__ epair) {
    int e = blockIdx.x * 256 + threadIdx.x;
    if (e >= N_EDGES) return;
    int u = src[e], v = dst[e];
    int pos = atomicAdd(&cursor[v * NPART + u / PSZ], 1);
    int2 p;
    p.x = u * 80;
    p.y = __float_as_int(d[u] * d[v]);
    epair[pos] = p;
}

__global__ __launch_bounds__(256) void scatter_self_kernel(const float* __restrict__ d,
                                                           int* __restrict__ cursor,
                                                           int2* __restrict__ epair) {
    int v = blockIdx.x * 256 + threadIdx.x;
    if (v >= N_NODES) return;
    int pos = atomicAdd(&cursor[v * NPART + v / PSZ], 1);
    float dv = d[v];
    int2 p;
    p.x = v * 80;
    p.y = __float_as_int(dv * dv);
    epair[pos] = p;
}

// W1 [512][256] f32 -> W1T [256][512] bf16 (col-major: per-col k contiguous)
__global__ __launch_bounds__(256) void cvt_w1_kernel(const float* __restrict__ W1,
                                                     short* __restrict__ W1T) {
    int lin = blockIdx.x * 256 + threadIdx.x;  // 131072
    int k = lin >> 8, n = lin & 255;
    W1T[n * 512 + k] = f2bf(W1[lin]);
}

// W2 [256][40] f32 -> W2T [64][256] bf16, rows >=40 zero
__global__ __launch_bounds__(256) void cvt_w2_kernel(const float* __restrict__ W2,
                                                     short* __restrict__ W2T) {
    int lin = blockIdx.x * 256 + threadIdx.x;  // 16384
    int n = lin >> 8, k = lin & 255;
    W2T[lin] = (n < N_CLS) ? f2bf(W2[k * N_CLS + n]) : (short)0;
}

// ---------------------------------------------------------------- fused MLP (MFMA)
// Block = 256 thr (4 waves), 64 rows. feat staged f32 via global_load_lds
// (width 16) into a double-buffered linear LDS tile; source address XOR-swizzled
// (16B units, u^=row&15) so ds_read_b128 fragment reads are bank-conflict-free.
// Counted vmcnt keeps the next tile's stage in flight across barriers.
// One 33.8KB LDS union -> 4 blocks/CU. Epilogue coalesced via LDS staging.
__global__ __launch_bounds__(256, 4) void mlp_kernel(const float* __restrict__ feat,
                                                     const short* __restrict__ W1T,
                                                     const float* __restrict__ b1,
                                                     const short* __restrict__ W2T,
                                                     const float* __restrict__ b2,
                                                     const float* __restrict__ temp,
                                                     short* __restrict__ h,
                                                     float* __restrict__ TH) {
    __shared__ union {
        float Af[2][64][64];                               // 32768 B (K-loop)
        short sH[64][264];                                 // 33792 B (phase B in)
        struct { short Ho[64][40]; float To[64][40]; } o;  // 15360 B (epilogue)
    } S;

    const int tid = threadIdx.x;
    const int rbase = blockIdx.x * 64;
    const int lane = tid & 63;
    const int wv = tid >> 6;       // wave 0..3
    const int quad = lane >> 4;    // 0..3
    const int l15 = lane & 15;

    f4_t acc[4][4];
#pragma unroll
    for (int m = 0; m < 4; ++m)
#pragma unroll
        for (int n = 0; n < 4; ++n) acc[m][n] = (f4_t)0.f;

    // staging geometry: thread t, issue i -> LDS bytes (i*256+t)*16 (linear),
    // i.e. row r = i*16 + (t>>4), 16B-unit u = t&15. Source unit = u ^ (r&15).
    const int sr = tid >> 4;       // 0..15
    const int su = tid & 15;

#define STAGE(BUF, KT)                                                          \
    {                                                                           \
        _Pragma("unroll")                                                       \
        for (int i = 0; i < 4; ++i) {                                           \
            int r = i * 16 + sr;                                                \
            int grow = rbase + r;                                               \
            if (grow >= N_NODES) grow = N_NODES - 1;                            \
            int usrc = su ^ (r & 15);                                           \
            const float* gp = feat + (size_t)grow * N_FEAT + (KT) * 64 + usrc * 4; \
            gload_lds16(gp, (char*)&S.Af[BUF][0][0] + (i * 256 + tid) * 16);    \
        }                                                                       \
    }

    STAGE(0, 0);  // prologue

#pragma unroll 1
    for (int kt = 0; kt < 8; ++kt) {
        const int b = kt & 1;
        // B fragments for this kt, issued BEFORE the stage so the compiler's
        // waits for them leave the stage loads in flight.
        short8 bfr[2][4];
        const short* wb = W1T + kt * 64;
#pragma unroll
        for (int kk2 = 0; kk2 < 2; ++kk2)
#pragma unroll
            for (int n = 0; n < 4; ++n)
                bfr[kk2][n] = *(const short8*)(wb + (wv * 64 + n * 16 + l15) * 512 +
                                               kk2 * 32 + quad * 8);
        __builtin_amdgcn_sched_barrier(0);   // keep bfr issue before stage
        if (kt < 7) {
            STAGE(b ^ 1, kt + 1);
            asm volatile("s_waitcnt vmcnt(4)" ::: "memory");  // tile kt + bfr done
        } else {
            asm volatile("s_waitcnt vmcnt(0)" ::: "memory");
        }
        __builtin_amdgcn_sched_barrier(0);
        __builtin_amdgcn_s_barrier();
        __builtin_amdgcn_sched_barrier(0);

#pragma unroll
        for (int kk2 = 0; kk2 < 2; ++kk2) {
            short8 af[4];
#pragma unroll
            for (int m = 0; m < 4; ++m) {
                int row = m * 16 + l15;
                int u0 = (kk2 << 3) + (quad << 1);
                f4_t lo = *(const f4_t*)&S.Af[b][row][((u0) ^ l15) << 2];
                f4_t hi = *(const f4_t*)&S.Af[b][row][((u0 + 1) ^ l15) << 2];
                union { unsigned u[4]; short8 s; } x;
                x.u[0] = cvtpk(lo[0], lo[1]);
                x.u[1] = cvtpk(lo[2], lo[3]);
                x.u[2] = cvtpk(hi[0], hi[1]);
                x.u[3] = cvtpk(hi[2], hi[3]);
                af[m] = x.s;
            }
#pragma unroll
            for (int m = 0; m < 4; ++m)
#pragma unroll
                for (int n = 0; n < 4; ++n)
                    acc[m][n] = __builtin_amdgcn_mfma_f32_16x16x32_bf16(
                        af[m], bfr[kk2][n], acc[m][n], 0, 0, 0);
        }
        __builtin_amdgcn_sched_barrier(0);   // ds_reads stay above this barrier
        __builtin_amdgcn_s_barrier();        // buf b free for restage at kt+1
    }
#undef STAGE

    // bias + relu -> sH (Af dead; all waves past final barrier)
#pragma unroll
    for (int n = 0; n < 4; ++n) {
        int col = wv * 64 + n * 16 + l15;
        float bb = b1[col];
#pragma unroll
        for (int m = 0; m < 4; ++m)
#pragma unroll
            for (int r = 0; r < 4; ++r) {
                float v = acc[m][n][r] + bb;
                S.sH[m * 16 + quad * 4 + r][col] = f2bf(v > 0.f ? v : 0.f);
            }
    }
    __syncthreads();

    // phase B: out = sH @ W2 + b2 ; W2 fragments from L1/L2 (32 KB, hot)
    f4_t accB[3];
#pragma unroll
    for (int n = 0; n < 3; ++n) accB[n] = (f4_t)0.f;
#pragma unroll
    for (int kk = 0; kk < 256; kk += 32) {
        short8 a = *(const short8*)&S.sH[wv * 16 + l15][kk + quad * 8];
#pragma unroll
        for (int n = 0; n < 3; ++n) {
            short8 b = *(const short8*)(W2T + (n * 16 + l15) * 256 + kk + quad * 8);
            accB[n] = __builtin_amdgcn_mfma_f32_16x16x32_bf16(a, b, accB[n], 0, 0, 0);
        }
    }
    __syncthreads();  // sH reads done -> epilogue staging may overwrite

    float t0 = temp[0];
#pragma unroll
    for (int n = 0; n < 3; ++n) {
        int col = n * 16 + l15;
        if (col < N_CLS) {
            float bb = b2[col];
#pragma unroll
            for (int r = 0; r < 4; ++r) {
                int row = wv * 16 + quad * 4 + r;
                float v = accB[n][r] + bb;
                S.o.Ho[row][col] = f2bf(v);
                S.o.To[row][col] = t0 * v;
            }
        }
    }
    __syncthreads();

    // coalesced 16B writes of h (bf16 [N][40]) and TH (f32 [N][40])
    int rows = N_NODES - rbase; if (rows > 64) rows = 64;  // 64 or 32 (both even)
    int nh = rows * 5;    // short8 chunks
    for (int i = tid; i < nh; i += 256)
        *(short8*)(h + (size_t)rbase * HROW + i * 8) =
            *(const short8*)((const short*)&S.o.Ho[0][0] + i * 8);
    int nt = rows * 10;   // f4 chunks
    for (int i = tid; i < nt; i += 256)
        *(f4_t*)(TH + (size_t)rbase * N_CLS + i * 4) =
            *(const f4_t*)((const float*)&S.o.To[0][0] + i * 4);
}

// ---------------------------------------------------------------- propagation
// Block = 51 nodes x 5 lanes (255 active). Block's epair slice staged into LDS
// (coalesced, dedups the 5x redundant reads, removes global latency from the
// address chain). Gathers 4-deep. Edges part-ordered for L2 locality.
__global__ __launch_bounds__(256, 8) void prop_kernel(const short* __restrict__ h,
                                                      short* __restrict__ hn,
                                                      const int* __restrict__ rowptrp,
                                                      const int2* __restrict__ epair,
                                                      float* __restrict__ TH,
                                                      const float* __restrict__ temp,
                                                      int kidx) {
    __shared__ long long sE[ECAP];
    __shared__ int sRP[64];

    const int t = threadIdx.x;
    const int v0 = blockIdx.x * PB;
    int nmax = N_NODES - v0; if (nmax > PB) nmax = PB;
    if (t <= nmax) sRP[t] = rowptrp[(v0 + t) * NPART];
    __syncthreads();
    const int S0 = sRP[0];
    const int count = sRP[nmax] - S0;

    const int n = t / 5;
    const int c = t - n * 5;
    const bool act = (n < nmax) && (t < 255);
    const int js = act ? (sRP[n] - S0) : 0;
    const int je = act ? (sRP[n + 1] - S0) : 0;
    const char* hB = (const char*)h + c * 16;

    f4_t a0 = (f4_t)0.f, a1 = (f4_t)0.f;
    int j = js;
    for (int base = 0; base < count; base += ECAP) {
        int lim = count - base; if (lim > ECAP) lim = ECAP;
        __syncthreads();
        for (int i = t; i < lim; i += 256)
            sE[i] = *(const long long*)(epair + (size_t)(S0 + base + i));
        __syncthreads();
        int jend = je - base; if (jend > lim) jend = lim;
        int jj = j - base;
        for (; jj + 4 <= jend; jj += 4) {
            long long r0 = sE[jj], r1 = sE[jj + 1], r2 = sE[jj + 2], r3 = sE[jj + 3];
            short8 h0 = *(const short8*)(hB + (unsigned)(int)r0);
            short8 h1 = *(const short8*)(hB + (unsigned)(int)r1);
            short8 h2 = *(const short8*)(hB + (unsigned)(int)r2);
            short8 h3 = *(const short8*)(hB + (unsigned)(int)r3);
            float w0 = __int_as_float((int)(r0 >> 32));
            float w1 = __int_as_float((int)(r1 >> 32));
            float w2 = __int_as_float((int)(r2 >> 32));
            float w3 = __int_as_float((int)(r3 >> 32));
#pragma unroll
            for (int i = 0; i < 4; ++i) {
                a0[i] += w0 * bf2f(h0[i]) + w1 * bf2f(h1[i]) + w2 * bf2f(h2[i]) +
                         w3 * bf2f(h3[i]);
                a1[i] += w0 * bf2f(h0[4 + i]) + w1 * bf2f(h1[4 + i]) +
                         w2 * bf2f(h2[4 + i]) + w3 * bf2f(h3[4 + i]);
            }
        }
        for (; jj < jend; ++jj) {
            long long r = sE[jj];
            short8 hb8 = *(const short8*)(hB + (unsigned)(int)r);
            float w = __int_as_float((int)(r >> 32));
#pragma unroll
            for (int i = 0; i < 4; ++i) {
                a0[i] += w * bf2f(hb8[i]);
                a1[i] += w * bf2f(hb8[4 + i]);
            }
        }
        if (jend > 0 && j < base + jend) j = base + jend;
    }

    if (!act) return;
    int v = v0 + n;
    float tk = temp[kidx];
    short8 ob;
#pragma unroll
    for (int i = 0; i < 4; ++i) { ob[i] = f2bf(a0[i]); ob[4 + i] = f2bf(a1[i]); }
    *(short8*)(hn + (size_t)v * HROW + c * 8) = ob;
    float* pt = TH + (size_t)v * N_CLS + c * 8;
    f4_t t0v = *(const f4_t*)pt;
    f4_t t1v = *(((const f4_t*)pt) + 1);
    t0v += tk * a0;
    t1v += tk * a1;
    *(f4_t*)pt = t0v;
    *(((f4_t*)pt) + 1) = t1v;
}

// ---------------------------------------------------------------- log_softmax
__global__ __launch_bounds__(256) void lsm_kernel(float* __restrict__ out) {
    int wid = (blockIdx.x * 256 + threadIdx.x) >> 6;
    int lane = threadIdx.x & 63;
    if (wid >= N_NODES) return;
    float x = (lane < N_CLS) ? out[wid * N_CLS + lane] : -INFINITY;
    float m = x;
#pragma unroll
    for (int o = 32; o > 0; o >>= 1) m = fmaxf(m, __shfl_xor(m, o, 64));
    float e = (lane < N_CLS) ? expf(x - m) : 0.f;
    float s = e;
#pragma unroll
    for (int o = 32; o > 0; o >>= 1) s += __shfl_xor(s, o, 64);
    float r = x - m - logf(s);
    if (lane < N_CLS) out[wid * N_CLS + lane] = r;
}

// ---------------------------------------------------------------- launch

extern "C" void kernel_launch(void* const* d_in, const int* in_sizes, int n_in,
                              void* d_out, int out_size, void* d_ws, size_t ws_size,
                              hipStream_t stream) {
    const float* feat = (const float*)d_in[0];
    const float* W1   = (const float*)d_in[1];
    const float* b1   = (const float*)d_in[2];
    const float* W2   = (const float*)d_in[3];
    const float* b2   = (const float*)d_in[4];
    const float* temp = (const float*)d_in[5];
    const int*   src  = (const int*)d_in[6];
    const int*   dst  = (const int*)d_in[7];
    float* out = (float*)d_out;

    // workspace layout (bytes). degp region reused for W1T/W2T after scan_write.
    char* ws = (char*)d_ws;
    int*   degp    = (int*)(ws + 0);          // 3,200,000 B (dead after scan_write)
    short* W1T     = (short*)(ws + 0);        //   262,144 B (overlaps degp)
    short* W2T     = (short*)(ws + 262144);   //    32,768 B (overlaps degp)
    float* dnorm   = (float*)(ws + 3200000);  //   400,000 B
    int*   rowptrp = (int*)(ws + 3600000);    // 3,200,004 B
    int*   cursor  = (int*)(ws + 6800016);    // 3,200,000 B
    int2*  epair   = (int2*)(ws + 10000016);  // 13,600,000 B
    short* h0      = (short*)(ws + 23600016); //  8,000,000 B (bf16, [N][40])
    short* h1      = (short*)(ws + 31600016); //  8,000,000 B
    int*   blocksum = (int*)(ws + 39600016);  //     3,128 B
    int*   blockoff = (int*)(ws + 39603152);  //     3,128 B  -> end 39,606,280

    init_degp_kernel<<<(NPN + 255) / 256, 256, 0, stream>>>(degp);
    count_dst_kernel<<<(N_EDGES + 255) / 256, 256, 0, stream>>>(src, dst, degp);
    rsqrt_deg_kernel<<<(N_NODES + 255) / 256, 256, 0, stream>>>(degp, dnorm);
    scan_partial_kernel<<<SCANB, 1024, 0, stream>>>(degp, blocksum);
    scan_blocks_kernel<<<1, 1024, 0, stream>>>(blocksum, blockoff);
    scan_write_kernel<<<SCANB, 1024, 0, stream>>>(degp, blockoff, rowptrp, cursor);
    cvt_w1_kernel<<<512, 256, 0, stream>>>(W1, W1T);
    cvt_w2_kernel<<<64, 256, 0, stream>>>(W2, W2T);
    scatter_edges_kernel<<<(N_EDGES + 255) / 256, 256, 0, stream>>>(src, dst, dnorm, cursor,
                                                                    epair);
    scatter_self_kernel<<<(N_NODES + 255) / 256, 256, 0, stream>>>(dnorm, cursor, epair);

    mlp_kernel<<<(N_NODES + 63) / 64, 256, 0, stream>>>(feat, W1T, b1, W2T, b2, temp, h0, out);

    short* hc = h0;
    short* hn = h1;
    for (int k = 0; k < K_HOPS; ++k) {
        prop_kernel<<<PGRID, 256, 0, stream>>>(hc, hn, rowptrp, epair, out, temp, k + 1);
        short* t = hc; hc = hn; hn = t;
    }

    lsm_kernel<<<(N_NODES / 4), 256, 0, stream>>>(out);
}